// Round 2
// baseline (715.873 us; speedup 1.0000x reference)
//
#include <hip/hip_runtime.h>

// DeepSet trimmed-mean pipeline, fp16 MFMA path.
// ws layout (bytes), total ~339.3 MB:
//   X16   @ 0          (64 MB)   fp16 [65536][512]
//   H1    @ 64MB       (128 MB)  fp16 [65536][1024]
//   encT  @ 192MB      (128 MB)  fp16 [64][1024 h][1024 n]
//   W1T   @ 320MB      (1 MB)    fp16 [1024][512]
//   W2T   @ 321MB      (2 MB)    fp16 [1024][1024]
//   agg   @ 323MB      (256 KB)  f32 [64][1024]
//   A3    @ +256KB     (256 KB)  f32 [64][1024]
//   nv,k  @ +512KB     (tiny)

typedef _Float16 half8  __attribute__((ext_vector_type(8)));
typedef _Float16 half4v __attribute__((ext_vector_type(4)));
typedef float    floatx4 __attribute__((ext_vector_type(4)));

#define GLD_LDS(g, l)                                                                     \
  __builtin_amdgcn_global_load_lds((const __attribute__((address_space(1))) void*)(g),    \
                                   (__attribute__((address_space(3))) void*)(l), 16, 0, 0)

// ---------------- P0: num_valid / k per batch ----------------
__global__ void prep_nv(const float* __restrict__ mask, int* __restrict__ nv_arr,
                        int* __restrict__ k_arr) {
  int b = blockIdx.x, lane = threadIdx.x;  // 64 threads
  const float4* mp = (const float4*)(mask + (b << 10));
  float s = 0.f;
#pragma unroll
  for (int i = 0; i < 4; ++i) {
    float4 v = mp[lane + i * 64];
    s += v.x + v.y + v.z + v.w;
  }
#pragma unroll
  for (int off = 32; off > 0; off >>= 1) s += __shfl_xor(s, off, 64);
  if (lane == 0) {
    int nv = (int)(s + 0.5f);
    int kk = (int)((float)nv * 0.1f);  // matches reference float32 * 0.1 -> int
    nv_arr[b] = nv;
    k_arr[b] = kk;
  }
}

// ---------------- P1 (merged): X conv (+ragged skip) & both W transposes --------
__device__ __forceinline__ void transpose_body(const float* __restrict__ W,
                                               _Float16* __restrict__ WT, int R, int C,
                                               int r0, int c0, _Float16 (*tile)[65]) {
  for (int i = threadIdx.x; i < 4096; i += 256) {
    int r = i >> 6, c = i & 63;
    tile[r][c] = (_Float16)W[(size_t)(r0 + r) * C + c0 + c];
  }
  __syncthreads();
  for (int i = threadIdx.x; i < 4096; i += 256) {
    int c = i >> 6, r = i & 63;
    WT[(size_t)(c0 + c) * R + r0 + r] = tile[r][c];
  }
}

__global__ __launch_bounds__(256) void preprocess(
    const float* __restrict__ X, _Float16* __restrict__ X16,
    const float* __restrict__ W1, _Float16* __restrict__ W1T,
    const float* __restrict__ W2, _Float16* __restrict__ W2T,
    const int* __restrict__ nv_arr) {
  __shared__ _Float16 tile[64][65];
  int bid = blockIdx.x;
  if (bid < 16384) {
    // conv X fp32->fp16; block covers rows 4*bid..4*bid+3 of one batch.
    int n0 = (bid << 2) & 1023;
    int batch = bid >> 8;
    int nv = nv_arr[batch];
    if (n0 >= ((nv + 255) & ~255)) return;  // GEMM1 tiles are 256-row granular
    int i = (bid * 256 + threadIdx.x) * 8;
    float4 a = *(const float4*)(X + i);
    float4 c = *(const float4*)(X + i + 4);
    half8 h;
    h[0] = (_Float16)a.x; h[1] = (_Float16)a.y; h[2] = (_Float16)a.z; h[3] = (_Float16)a.w;
    h[4] = (_Float16)c.x; h[5] = (_Float16)c.y; h[6] = (_Float16)c.z; h[7] = (_Float16)c.w;
    *(half8*)(X16 + i) = h;
  } else if (bid < 16384 + 128) {
    int id = bid - 16384;  // W1: R=512, C=1024; 8 x 16 tiles
    transpose_body(W1, W1T, 512, 1024, (id & 7) * 64, (id >> 3) * 64, tile);
  } else {
    int id = bid - 16512;  // W2: R=1024, C=1024; 16 x 16 tiles
    transpose_body(W2, W2T, 1024, 1024, (id & 15) * 64, (id >> 4) * 64, tile);
  }
}

// ---------------- GEMM: D[i][j] = sum_k Aop[i][k]*Bop[j][k] ----------------
// 256x256 tile, BK=64, 8 waves (2 i-dim x 4 j-dim), 512 threads, 128 KiB LDS
// (2 K-tile double buffer). TWO barriers per K-tile (vs 8 in R1):
//   b2 (after p1, + per-wave lgkmcnt(0)): buf[CUR] fully consumed into registers
//       -> A(kt+2)/B(kt+2) may overwrite it (same parity -> CUR buffer).
//   b1 (after p2, + counted vmcnt(4)): tile kt+1 staging landed -> p3 may read it.
// Fragment reads are software-pipelined one phase ahead and issue UNDER MFMA
// (plain-C ds_reads; compiler emits exact counted lgkmcnt):
//   p3 of kt-1: af_lo(kt)[8] + bf(kt,jh0)[4];  p0 of kt: bf(kt,jh1)[4];
//   p1 of kt: af_hi(kt)[8].
// Staging (8 gld_lds/K-tile, 4@p2 + 4@p3, target buf[CUR]): issued a full K-tile
// before its b1 wait -> ~4 phases (~1000 cyc) slack >= HBM latency. Steady-state
// outstanding <= 8, never drained to 0 until the tail.
// Quad order: p0 (ih0,jh0), p1 (ih0,jh1), p2 (ih1,jh0), p3 (ih1,jh1).
// B-frags double-buffered in registers (bfA/bfB, compile-time parity via
// pair-unrolled loop); A-frags single-buffered (af_lo free after p1, af_hi after p3).
// LDS swizzle: [256][64] halves/operand, 16B chunk c of row r at slot (c ^ (r&7));
// permutation applied to the GLOBAL source address (global_load_lds lands linear).
// XCD-aware grid: fat = ((bid>>5)<<3)|(bid&7), thin = (bid>>3)&3 — the 4 blocks
// sharing a fat tile are consecutive slots on ONE XCD (round-robin bid%8).
// MODE 1: i=h(thin), j=m(fat). out = relu(D+bias[i]) -> H1[m][h].
// MODE 2: i=m(fat), j=h(thin). out = D + bias[j] -> encT[b][h][n].
template <int KDIM, int MODE>
__global__ __launch_bounds__(512, 2) void gemm_kernel(
    const _Float16* __restrict__ Aop, const _Float16* __restrict__ Bop,
    const float* __restrict__ bias, const int* __restrict__ nv_arr,
    _Float16* __restrict__ outp) {
  constexpr int NT = KDIM / 64;  // 8 or 16 K-tiles (even)
  __shared__ __align__(16) _Float16 lds[2][2][256 * 64];  // [buf][op A/B][row*64+k]

  int bid = blockIdx.x;
  int fat = ((((bid >> 5) << 3) | (bid & 7))) << 8;
  int thin = ((bid >> 3) & 3) << 8;
  int i0, j0;
  if (MODE == 1) {
    i0 = thin; j0 = fat;
    if ((j0 & 1023) >= nv_arr[j0 >> 10]) return;
  } else {
    i0 = fat; j0 = thin;
    if ((i0 & 1023) >= nv_arr[i0 >> 10]) return;
  }
  const int t = threadIdx.x, lane = t & 63;
  const int wv = t >> 6, wm = wv & 1, wn = wv >> 1;  // wave -> (i-half, j-quarter)
  const int lr = lane & 15, q = lane >> 4;
  const int swz = (q ^ (lr & 7)) * 8;  // ds_read chunk swizzle (row&7 == lr&7 here)

  // staging addresses: thread t covers chunk (R*512+t): row = 64R + (t>>3),
  // slot = t&7, pre-swizzled global chunk gch = slot ^ (row&7) = (t&7)^((t>>3)&7).
  const int gch = (t & 7) ^ ((t >> 3) & 7);
  const _Float16* gA = Aop + (size_t)(i0 + (t >> 3)) * KDIM + gch * 8;
  const _Float16* gB = Bop + (size_t)(j0 + (t >> 3)) * KDIM + gch * 8;

#define STG(OP, BUF, KT, R)                                                   \
  GLD_LDS(((OP) ? gB : gA) + (size_t)(R) * 64 * KDIM + (size_t)(KT) * 64,     \
          &lds[BUF][OP][((R) * 512 + (t & ~63)) * 8])

  floatx4 acc[8][4] = {};
  half8 af_lo[4][2], af_hi[4][2];     // A frags, current tile (lo: rows 0-63, hi: 64-127)
  half8 bfA[2][2][2], bfB[2][2][2];   // B frags [jh][g][kk], double-buffered by tile parity

#define LD_A(BUF, IH, DST)                                                    \
  _Pragma("unroll") for (int f = 0; f < 4; ++f)                               \
  _Pragma("unroll") for (int kk = 0; kk < 2; ++kk)                            \
      DST[f][kk] = *(const half8*)&lds[BUF][0]                                \
          [(((wm << 7) + ((IH) << 6) + (f << 4) + lr) << 6) + (swz ^ (kk << 5))];

#define LD_B_HALF(BUF, SET, JH)                                               \
  _Pragma("unroll") for (int g = 0; g < 2; ++g)                               \
  _Pragma("unroll") for (int kk = 0; kk < 2; ++kk)                            \
      SET[JH][g][kk] = *(const half8*)&lds[BUF][1]                            \
          [(((wn << 6) + ((JH) << 5) + (g << 4) + lr) << 6) + (swz ^ (kk << 5))];

#define MFMA_QUAD(IH, JH, AF, SET)                                            \
  __builtin_amdgcn_s_setprio(1);                                              \
  _Pragma("unroll") for (int f = 0; f < 4; ++f)                               \
  _Pragma("unroll") for (int g = 0; g < 2; ++g)                               \
  _Pragma("unroll") for (int kk = 0; kk < 2; ++kk)                            \
      acc[((IH) << 2) + f][((JH) << 1) + g] =                                 \
          __builtin_amdgcn_mfma_f32_16x16x32_f16(                             \
              AF[f][kk], SET[JH][g][kk], acc[((IH) << 2) + f][((JH) << 1) + g], 0, 0, 0); \
  __builtin_amdgcn_s_setprio(0);

// One K-tile. CUR = KT&1 (compile-time via unroll). Stages tile KT+2 into buf[CUR].
#define TILE(KT, CUR, NXT, BFC, BFN, DO_STG, DO_NEXT)                         \
  {                                                                           \
    /* p0 */                                                                  \
    LD_B_HALF(CUR, BFC, 1);                                                   \
    MFMA_QUAD(0, 0, af_lo, BFC);                                              \
    /* p1 */                                                                  \
    LD_A(CUR, 1, af_hi);                                                      \
    MFMA_QUAD(0, 1, af_lo, BFC);                                              \
    asm volatile("s_waitcnt lgkmcnt(0)" ::: "memory");                        \
    __builtin_amdgcn_sched_barrier(0);                                        \
    __builtin_amdgcn_s_barrier(); /* b2: buf[CUR] fully consumed */           \
    __builtin_amdgcn_sched_barrier(0);                                        \
    /* p2 */                                                                  \
    if (DO_STG) { STG(0, CUR, (KT) + 2, 0); STG(0, CUR, (KT) + 2, 1);         \
                  STG(1, CUR, (KT) + 2, 0); STG(1, CUR, (KT) + 2, 1); }       \
    MFMA_QUAD(1, 0, af_hi, BFC);                                              \
    if (DO_NEXT) {                                                            \
      if (DO_STG) { asm volatile("s_waitcnt vmcnt(4)" ::: "memory"); }        \
      else        { asm volatile("s_waitcnt vmcnt(0)" ::: "memory"); }        \
      __builtin_amdgcn_sched_barrier(0);                                      \
      __builtin_amdgcn_s_barrier(); /* b1: tile KT+1 staged */                \
      __builtin_amdgcn_sched_barrier(0);                                      \
    }                                                                         \
    /* p3 */                                                                  \
    if (DO_STG) { STG(0, CUR, (KT) + 2, 2); STG(0, CUR, (KT) + 2, 3);         \
                  STG(1, CUR, (KT) + 2, 2); STG(1, CUR, (KT) + 2, 3); }       \
    if (DO_NEXT) { LD_A(NXT, 0, af_lo); LD_B_HALF(NXT, BFN, 0); }             \
    MFMA_QUAD(1, 1, af_hi, BFC);                                              \
  }

  // prologue: tile0 -> buf0 (oldest 8 loads), tile1 -> buf1 (next 8).
  STG(0, 0, 0, 0); STG(0, 0, 0, 1); STG(0, 0, 0, 2); STG(0, 0, 0, 3);
  STG(1, 0, 0, 0); STG(1, 0, 0, 1); STG(1, 0, 0, 2); STG(1, 0, 0, 3);
  STG(0, 1, 1, 0); STG(0, 1, 1, 1); STG(0, 1, 1, 2); STG(0, 1, 1, 3);
  STG(1, 1, 1, 0); STG(1, 1, 1, 1); STG(1, 1, 1, 2); STG(1, 1, 1, 3);
  asm volatile("s_waitcnt vmcnt(8)" ::: "memory");  // tile0 done; tile1 in flight
  __builtin_amdgcn_s_barrier();
  __builtin_amdgcn_sched_barrier(0);
  LD_A(0, 0, af_lo);
  LD_B_HALF(0, bfA, 0);

  for (int kt = 0; kt < NT - 2; kt += 2) {
    TILE(kt, 0, 1, bfA, bfB, 1, 1);
    TILE(kt + 1, 1, 0, bfB, bfA, 1, 1);
  }
  TILE(NT - 2, 0, 1, bfA, bfB, 0, 1);  // drains all staging at its b1
  TILE(NT - 1, 1, 0, bfB, bfA, 0, 0);

  // epilogue: lane holds rows i = base..base+3 (contiguous), col j = lr per 16x16 tile
  if (MODE == 1) {
#pragma unroll
    for (int mi = 0; mi < 8; ++mi) {
      int ih = i0 + (wm << 7) + (mi << 4) + (q << 2);
      floatx4 bb = *(const floatx4*)&bias[ih];
#pragma unroll
      for (int nj = 0; nj < 4; ++nj) {
        int j = j0 + (wn << 6) + (nj << 4) + lr;
        floatx4 v = acc[mi][nj];
        half4v hv;
#pragma unroll
        for (int r = 0; r < 4; ++r) hv[r] = (_Float16)fmaxf(v[r] + bb[r], 0.f);
        *(half4v*)&outp[(size_t)j * 1024 + ih] = hv;  // H1[m][h..h+3]
      }
    }
  } else {
#pragma unroll
    for (int nj = 0; nj < 4; ++nj) {
      int j = j0 + (wn << 6) + (nj << 4) + lr;  // h
      float bj = bias[j];
#pragma unroll
      for (int mi = 0; mi < 8; ++mi) {
        int im = i0 + (wm << 7) + (mi << 4) + (q << 2);  // m
        int bb = im >> 10, n = im & 1023;
        floatx4 v = acc[mi][nj];
        half4v hv;
#pragma unroll
        for (int r = 0; r < 4; ++r) hv[r] = (_Float16)(v[r] + bj);
        *(half4v*)&outp[((size_t)bb << 20) + ((size_t)j << 10) + (size_t)n] = hv;
      }
    }
  }
}

// ---------------- Trim v3: count-only histogram + in-register sums ----------------
// One wave per column (b,h). 1024 u32 count bins (16 KB/block -> 10 blocks/CU).
// Locate boundary bins from count scan; all sums (s(b1), s(b2), mid-sum) computed
// in-register via predicated wave reductions over the 16 loaded values/lane.
// Physical slot of logical uint4-chunk j of lane L: L*4 + (j ^ ((L>>1)&3))  (2-way
// free bank pattern for the b128 init/readback).
#define NB 1024
__global__ __launch_bounds__(256) void trim_kernel(const _Float16* __restrict__ encT,
                                                   const int* __restrict__ nv_arr,
                                                   const int* __restrict__ k_arr,
                                                   float* __restrict__ agg) {
  __shared__ unsigned int cnt[4 * NB];  // 16 KB, wave-private slices
  int t = threadIdx.x, lane = t & 63, w = t >> 6;
  int blk = blockIdx.x;
  int batch = blk >> 8;
  int h = ((blk & 255) << 2) + w;
  unsigned int* cw = cnt + w * NB;
  uint4* cp = (uint4*)cw;
  {
    uint4 z = {0u, 0u, 0u, 0u};
#pragma unroll
    for (int i = 0; i < 4; ++i) cp[lane * 4 + (i ^ ((lane >> 1) & 3))] = z;
  }

  int nv = nv_arr[batch], kk = k_arr[batch];
  const _Float16* col = encT + ((size_t)batch << 20) + ((size_t)h << 10);
  const uint4* p = (const uint4*)col + lane * 2;
  uint4 u0 = p[0], u1 = p[1];
  unsigned vals[8] = {u0.x, u0.y, u0.z, u0.w, u1.x, u1.y, u1.z, u1.w};
  int nvalid = nv - lane * 16;  // may be <=0 or >=16

  float vv[16];
  int bn[16];
#pragma unroll
  for (int d = 0; d < 8; ++d) {
    unsigned u = vals[d];
#pragma unroll
    for (int sub = 0; sub < 2; ++sub) {
      int idx = d * 2 + sub;
      unsigned short bits = (unsigned short)(sub ? (u >> 16) : (u & 0xffffu));
      _Float16 hvv;
      __builtin_memcpy(&hvv, &bits, 2);
      float v = (float)hvv;
      if (idx < nvalid) {
        v = fminf(fmaxf(v, -8.0f), 7.999f);
        int bin = (int)((v + 8.0f) * 64.0f);
        bin = min(NB - 1, bin);
        vv[idx] = v;
        bn[idx] = bin;
        int Lb = bin >> 4, jc = (bin >> 2) & 3;
        int phys = ((Lb << 2) + (jc ^ ((Lb >> 1) & 3))) * 4 + (bin & 3);
        atomicAdd(&cw[phys], 1u);
      } else {
        vv[idx] = 0.f;
        bn[idx] = -1;
      }
    }
  }

  // readback own 16 counts (logical bins [lane*16, lane*16+16))
  int c[16];
  {
    uint4 rb[4];
#pragma unroll
    for (int i = 0; i < 4; ++i) rb[i] = cp[lane * 4 + (i ^ ((lane >> 1) & 3))];
#pragma unroll
    for (int i = 0; i < 4; ++i) {
      c[4 * i] = (int)rb[i].x; c[4 * i + 1] = (int)rb[i].y;
      c[4 * i + 2] = (int)rb[i].z; c[4 * i + 3] = (int)rb[i].w;
    }
  }
  int ct = 0;
#pragma unroll
  for (int i = 0; i < 16; ++i) ct += c[i];
  // exclusive scan of chunk totals across lanes
  int ci = ct;
#pragma unroll
  for (int off = 1; off < 64; off <<= 1) {
    int cu = __shfl_up(ci, off, 64);
    if (lane >= off) ci += cu;
  }
  int cex = ci - ct;
  int r1 = kk, r2 = nv - kk;
  // locate boundary bins; pack (bin<<12)|cex_at_bin, broadcast via max-reduce
  int p1 = -1, p2 = -1;
  {
    int run = cex;
#pragma unroll
    for (int i = 0; i < 16; ++i) {
      int cc = c[i];
      if (run < r1 && r1 <= run + cc) p1 = ((lane * 16 + i) << 12) | run;
      if (run < r2 && r2 <= run + cc) p2 = ((lane * 16 + i) << 12) | run;
      run += cc;
    }
  }
#pragma unroll
  for (int off = 32; off > 0; off >>= 1) {
    p1 = max(p1, __shfl_xor(p1, off, 64));
    p2 = max(p2, __shfl_xor(p2, off, 64));
  }
  int b1 = p1 >> 12, cex1 = p1 & 4095;
  int b2 = p2 >> 12, cex2 = p2 & 4095;
  // predicated in-register sums
  float s1 = 0.f, s2 = 0.f, tm = 0.f;
  int c1 = 0, c2 = 0;
#pragma unroll
  for (int i = 0; i < 16; ++i) {
    int b = bn[i];
    float v = vv[i];
    if (b == b1) { s1 += v; c1++; }
    if (b == b2) { s2 += v; c2++; }
    if (b > b1 && b < b2) tm += v;
  }
#pragma unroll
  for (int off = 32; off > 0; off >>= 1) {
    s1 += __shfl_xor(s1, off, 64);
    s2 += __shfl_xor(s2, off, 64);
    tm += __shfl_xor(tm, off, 64);
    c1 += __shfl_xor(c1, off, 64);
    c2 += __shfl_xor(c2, off, 64);
  }
  float mid;
  if (b1 == b2) {
    mid = (float)(r2 - r1) * (s1 / (float)c1);
  } else {
    mid = (float)(cex1 + c1 - r1) * (s1 / (float)c1) + tm +
          (float)(r2 - cex2) * (s2 / (float)c2);
  }
  if (lane == 0) {
    agg[(batch << 10) + h] = mid / (float)(nv - 2 * kk);
  }
}

// ---------------- Decode 1 (K-split GEMV): A3 = relu(agg @ W3 + b3) ----------------
__global__ __launch_bounds__(256) void decode1(const float* __restrict__ agg,
                                               const float* __restrict__ W3,
                                               const float* __restrict__ b3,
                                               float* __restrict__ A3) {
  __shared__ float al[1024];
  __shared__ float red[256];
  int b = blockIdx.x, hb = blockIdx.y, t = threadIdx.x;
  for (int i = t; i < 1024; i += 256) al[i] = agg[(b << 10) + i];
  __syncthreads();
  int hl = t & 63, ks = t >> 6;
  int h = hb * 64 + hl;
  const float* wp = W3 + (size_t)(ks * 256) * 1024 + h;
  const float* ap = al + ks * 256;
  float acc = 0.f;
#pragma unroll 8
  for (int k = 0; k < 256; ++k) acc = fmaf(ap[k], wp[(size_t)k * 1024], acc);
  red[t] = acc;
  __syncthreads();
  if (t < 64) {
    float s = red[t] + red[t + 64] + red[t + 128] + red[t + 192] + b3[hb * 64 + t];
    A3[(b << 10) + hb * 64 + t] = fmaxf(s, 0.f);
  }
}

__global__ void decode2(const float* __restrict__ A3, const float* __restrict__ W4,
                        const float* __restrict__ b4, float* __restrict__ outp) {
  __shared__ float red[4][10];
  int b = blockIdx.x, t = threadIdx.x, lane = t & 63, w = t >> 6;
  float part[10];
#pragma unroll
  for (int o = 0; o < 10; ++o) part[o] = 0.f;
#pragma unroll
  for (int jj = 0; jj < 4; ++jj) {
    int h2 = jj * 256 + t;
    float a = A3[(b << 10) + h2];
#pragma unroll
    for (int o = 0; o < 10; ++o) part[o] = fmaf(a, W4[h2 * 10 + o], part[o]);
  }
#pragma unroll
  for (int o = 0; o < 10; ++o)
#pragma unroll
    for (int off = 32; off > 0; off >>= 1) part[o] += __shfl_xor(part[o], off, 64);
  if (lane == 0)
#pragma unroll
    for (int o = 0; o < 10; ++o) red[w][o] = part[o];
  __syncthreads();
  if (t < 10) outp[b * 10 + t] = b4[t] + red[0][t] + red[1][t] + red[2][t] + red[3][t];
}

extern "C" void kernel_launch(void* const* d_in, const int* in_sizes, int n_in,
                              void* d_out, int out_size, void* d_ws, size_t ws_size,
                              hipStream_t stream) {
  const float* X = (const float*)d_in[0];
  const float* mask = (const float*)d_in[1];
  const float* W1 = (const float*)d_in[2];
  const float* b1 = (const float*)d_in[3];
  const float* W2 = (const float*)d_in[4];
  const float* b2 = (const float*)d_in[5];
  const float* W3 = (const float*)d_in[6];
  const float* b3 = (const float*)d_in[7];
  const float* W4 = (const float*)d_in[8];
  const float* b4 = (const float*)d_in[9];
  float* outp = (float*)d_out;
  char* ws = (char*)d_ws;

  _Float16* X16 = (_Float16*)(ws);
  _Float16* H1 = (_Float16*)(ws + 67108864ull);
  _Float16* encT = (_Float16*)(ws + 201326592ull);
  _Float16* W1T = (_Float16*)(ws + 335544320ull);
  _Float16* W2T = (_Float16*)(ws + 336592896ull);
  float* agg = (float*)(ws + 338690048ull);
  float* A3 = (float*)(ws + 338952192ull);
  int* nv_arr = (int*)(ws + 339214336ull);
  int* k_arr = (int*)(ws + 339214592ull);

  prep_nv<<<64, 64, 0, stream>>>(mask, nv_arr, k_arr);
  preprocess<<<16768, 256, 0, stream>>>(X, X16, W1, W1T, W2, W2T, nv_arr);
  gemm_kernel<512, 1><<<1024, 512, 0, stream>>>(W1T, X16, b1, nv_arr, H1);
  gemm_kernel<1024, 2><<<1024, 512, 0, stream>>>(H1, W2T, b2, nv_arr, encT);
  trim_kernel<<<16384, 256, 0, stream>>>(encT, nv_arr, k_arr, agg);
  decode1<<<dim3(64, 16), 256, 0, stream>>>(agg, W3, b3, A3);
  decode2<<<64, 256, 0, stream>>>(A3, W4, b4, outp);
}

// Round 3
// 532.263 us; speedup vs baseline: 1.3450x; 1.3450x over previous
//
#include <hip/hip_runtime.h>

// DeepSet trimmed-mean pipeline, fp16 MFMA path.
// ws layout (bytes), total ~339.3 MB:
//   X16   @ 0          (64 MB)   fp16 [65536][512]
//   H1    @ 64MB       (128 MB)  fp16 [65536][1024]
//   encT  @ 192MB      (128 MB)  fp16 [64][1024 h][1024 n]
//   W1T   @ 320MB      (1 MB)    fp16 [1024][512]
//   W2T   @ 321MB      (2 MB)    fp16 [1024][1024]
//   agg   @ 323MB      (256 KB)  f32 [64][1024]
//   A3    @ +256KB     (256 KB)  f32 [64][1024]
//   nv,k  @ +512KB     (tiny)

typedef _Float16 half8  __attribute__((ext_vector_type(8)));
typedef _Float16 half4v __attribute__((ext_vector_type(4)));
typedef float    floatx4 __attribute__((ext_vector_type(4)));

#define GLD_LDS(g, l)                                                                     \
  __builtin_amdgcn_global_load_lds((const __attribute__((address_space(1))) void*)(g),    \
                                   (__attribute__((address_space(3))) void*)(l), 16, 0, 0)

// ---------------- P0: num_valid / k per batch ----------------
__global__ void prep_nv(const float* __restrict__ mask, int* __restrict__ nv_arr,
                        int* __restrict__ k_arr) {
  int b = blockIdx.x, lane = threadIdx.x;  // 64 threads
  const float4* mp = (const float4*)(mask + (b << 10));
  float s = 0.f;
#pragma unroll
  for (int i = 0; i < 4; ++i) {
    float4 v = mp[lane + i * 64];
    s += v.x + v.y + v.z + v.w;
  }
#pragma unroll
  for (int off = 32; off > 0; off >>= 1) s += __shfl_xor(s, off, 64);
  if (lane == 0) {
    int nv = (int)(s + 0.5f);
    int kk = (int)((float)nv * 0.1f);  // matches reference float32 * 0.1 -> int
    nv_arr[b] = nv;
    k_arr[b] = kk;
  }
}

// ---------------- P1 (merged): X conv (+ragged skip) & both W transposes --------
__device__ __forceinline__ void transpose_body(const float* __restrict__ W,
                                               _Float16* __restrict__ WT, int R, int C,
                                               int r0, int c0, _Float16 (*tile)[65]) {
  for (int i = threadIdx.x; i < 4096; i += 256) {
    int r = i >> 6, c = i & 63;
    tile[r][c] = (_Float16)W[(size_t)(r0 + r) * C + c0 + c];
  }
  __syncthreads();
  for (int i = threadIdx.x; i < 4096; i += 256) {
    int c = i >> 6, r = i & 63;
    WT[(size_t)(c0 + c) * R + r0 + r] = tile[r][c];
  }
}

__global__ __launch_bounds__(256) void preprocess(
    const float* __restrict__ X, _Float16* __restrict__ X16,
    const float* __restrict__ W1, _Float16* __restrict__ W1T,
    const float* __restrict__ W2, _Float16* __restrict__ W2T,
    const int* __restrict__ nv_arr) {
  __shared__ _Float16 tile[64][65];
  int bid = blockIdx.x;
  if (bid < 16384) {
    // conv X fp32->fp16; block covers rows 4*bid..4*bid+3 of one batch.
    int n0 = (bid << 2) & 1023;
    int batch = bid >> 8;
    int nv = nv_arr[batch];
    if (n0 >= ((nv + 255) & ~255)) return;  // GEMM1 tiles are 256-row granular
    int i = (bid * 256 + threadIdx.x) * 8;
    float4 a = *(const float4*)(X + i);
    float4 c = *(const float4*)(X + i + 4);
    half8 h;
    h[0] = (_Float16)a.x; h[1] = (_Float16)a.y; h[2] = (_Float16)a.z; h[3] = (_Float16)a.w;
    h[4] = (_Float16)c.x; h[5] = (_Float16)c.y; h[6] = (_Float16)c.z; h[7] = (_Float16)c.w;
    *(half8*)(X16 + i) = h;
  } else if (bid < 16384 + 128) {
    int id = bid - 16384;  // W1: R=512, C=1024; 8 x 16 tiles
    transpose_body(W1, W1T, 512, 1024, (id & 7) * 64, (id >> 3) * 64, tile);
  } else {
    int id = bid - 16512;  // W2: R=1024, C=1024; 16 x 16 tiles
    transpose_body(W2, W2T, 1024, 1024, (id & 15) * 64, (id >> 4) * 64, tile);
  }
}

// ---------------- GEMM: D[i][j] = sum_k Aop[i][k]*Bop[j][k] ----------------
// 256x256 tile, BK=64, 8 waves (2 i-dim x 4 j-dim), 512 threads, 128 KiB LDS
// (2 K-tile double buffer). TWO barriers per K-tile, frag footprint = 64 VGPR
// (R2 post-mortem: af_lo/af_hi + bfA/bfB = 128 frag VGPRs blew the 128-cap
// [acc=128 AGPR, launch_bounds(512,2) => 256 unified] -> scratch spill, HBM
// traffic doubled. This version reuses ONE af[4][2] lo->hi and ONE bf set.)
// Per K-tile kt (CUR = kt&1):
//   [b1 entered: buf[CUR] staged]
//   p0: ds_read A-lo(8) + B-jh0(4) + B-jh1(4); QUAD(0,0); QUAD(0,1)
//       LD_A hi -> af (reuse; quads consumed af); lgkmcnt(0); b2
//       [b2: all reads from buf[CUR] landed in regs -> buffer overwritable]
//   p1: STG tile kt+2 -> buf[CUR] (8 gld_lds); QUAD(1,0); QUAD(1,1)
//       vmcnt(8) [newest 8 = kt+2's; forces kt+1 complete, issued ~1.5 tiles
//       earlier]; b1. Steady-state vmcnt never drains to 0.
// LDS swizzle: [256][64] halves/operand, 16B chunk c of row r at slot (c ^ (r&7));
// permutation applied to the GLOBAL source address (global_load_lds lands linear).
// XCD-aware grid: fat = ((bid>>5)<<3)|(bid&7), thin = (bid>>3)&3 — the 4 blocks
// sharing a fat tile are consecutive slots on ONE XCD (round-robin bid%8).
// MODE 1: i=h(thin), j=m(fat). out = relu(D+bias[i]) -> H1[m][h].
// MODE 2: i=m(fat), j=h(thin). out = D + bias[j] -> encT[b][h][n].
template <int KDIM, int MODE>
__global__ __launch_bounds__(512, 2) void gemm_kernel(
    const _Float16* __restrict__ Aop, const _Float16* __restrict__ Bop,
    const float* __restrict__ bias, const int* __restrict__ nv_arr,
    _Float16* __restrict__ outp) {
  constexpr int NT = KDIM / 64;  // 8 or 16 K-tiles (even)
  __shared__ __align__(16) _Float16 lds[2][2][256 * 64];  // [buf][op A/B][row*64+k]

  int bid = blockIdx.x;
  int fat = ((((bid >> 5) << 3) | (bid & 7))) << 8;
  int thin = ((bid >> 3) & 3) << 8;
  int i0, j0;
  if (MODE == 1) {
    i0 = thin; j0 = fat;
    if ((j0 & 1023) >= nv_arr[j0 >> 10]) return;
  } else {
    i0 = fat; j0 = thin;
    if ((i0 & 1023) >= nv_arr[i0 >> 10]) return;
  }
  const int t = threadIdx.x, lane = t & 63;
  const int wv = t >> 6, wm = wv & 1, wn = wv >> 1;  // wave -> (i-half, j-quarter)
  const int lr = lane & 15, q = lane >> 4;
  const int swz = (q ^ (lr & 7)) * 8;  // ds_read chunk swizzle (row&7 == lr&7 here)

  // staging addresses: thread t covers chunk (R*512+t): row = 64R + (t>>3),
  // slot = t&7, pre-swizzled global chunk gch = slot ^ (row&7) = (t&7)^((t>>3)&7).
  const int gch = (t & 7) ^ ((t >> 3) & 7);
  const _Float16* gA = Aop + (size_t)(i0 + (t >> 3)) * KDIM + gch * 8;
  const _Float16* gB = Bop + (size_t)(j0 + (t >> 3)) * KDIM + gch * 8;

#define STG(OP, BUF, KT, R)                                                   \
  GLD_LDS(((OP) ? gB : gA) + (size_t)(R) * 64 * KDIM + (size_t)(KT) * 64,     \
          &lds[BUF][OP][((R) * 512 + (t & ~63)) * 8])

  floatx4 acc[8][4] = {};
  half8 af[4][2];     // A frags (reused: rows 0-63 then 64-127 of wave's half)
  half8 bf[2][2][2];  // B frags [jh][g][kk], both j-halves of current tile

#define LD_A(BUF, IH)                                                         \
  _Pragma("unroll") for (int f = 0; f < 4; ++f)                               \
  _Pragma("unroll") for (int kk = 0; kk < 2; ++kk)                            \
      af[f][kk] = *(const half8*)&lds[BUF][0]                                 \
          [(((wm << 7) + ((IH) << 6) + (f << 4) + lr) << 6) + (swz ^ (kk << 5))];

#define LD_B_HALF(BUF, JH)                                                    \
  _Pragma("unroll") for (int g = 0; g < 2; ++g)                               \
  _Pragma("unroll") for (int kk = 0; kk < 2; ++kk)                            \
      bf[JH][g][kk] = *(const half8*)&lds[BUF][1]                             \
          [(((wn << 6) + ((JH) << 5) + (g << 4) + lr) << 6) + (swz ^ (kk << 5))];

#define MFMA_QUAD(IH, JH)                                                     \
  __builtin_amdgcn_s_setprio(1);                                              \
  _Pragma("unroll") for (int f = 0; f < 4; ++f)                               \
  _Pragma("unroll") for (int g = 0; g < 2; ++g)                               \
  _Pragma("unroll") for (int kk = 0; kk < 2; ++kk)                            \
      acc[((IH) << 2) + f][((JH) << 1) + g] =                                 \
          __builtin_amdgcn_mfma_f32_16x16x32_f16(                             \
              af[f][kk], bf[JH][g][kk], acc[((IH) << 2) + f][((JH) << 1) + g], 0, 0, 0); \
  __builtin_amdgcn_s_setprio(0);

// One K-tile. CUR is a literal 0/1. Stages tile KT+2 into buf[CUR].
#define TILE(KT, CUR, DO_STG, DO_B1)                                          \
  {                                                                           \
    LD_A(CUR, 0);                                                             \
    LD_B_HALF(CUR, 0);                                                        \
    LD_B_HALF(CUR, 1);                                                        \
    MFMA_QUAD(0, 0);                                                          \
    MFMA_QUAD(0, 1);                                                          \
    LD_A(CUR, 1);                                                             \
    asm volatile("s_waitcnt lgkmcnt(0)" ::: "memory");                        \
    __builtin_amdgcn_sched_barrier(0);                                        \
    __builtin_amdgcn_s_barrier(); /* b2: buf[CUR] fully consumed */           \
    __builtin_amdgcn_sched_barrier(0);                                        \
    if (DO_STG) { STG(0, CUR, (KT) + 2, 0); STG(0, CUR, (KT) + 2, 1);         \
                  STG(1, CUR, (KT) + 2, 0); STG(1, CUR, (KT) + 2, 1);         \
                  STG(0, CUR, (KT) + 2, 2); STG(0, CUR, (KT) + 2, 3);         \
                  STG(1, CUR, (KT) + 2, 2); STG(1, CUR, (KT) + 2, 3); }       \
    MFMA_QUAD(1, 0);                                                          \
    MFMA_QUAD(1, 1);                                                          \
    if (DO_B1) {                                                              \
      if (DO_STG) { asm volatile("s_waitcnt vmcnt(8)" ::: "memory"); }        \
      else        { asm volatile("s_waitcnt vmcnt(0)" ::: "memory"); }        \
      __builtin_amdgcn_sched_barrier(0);                                      \
      __builtin_amdgcn_s_barrier(); /* b1: tile KT+1 staged */                \
      __builtin_amdgcn_sched_barrier(0);                                      \
    }                                                                         \
  }

  // prologue: tile0 -> buf0 (oldest 8 loads), tile1 -> buf1 (next 8).
  STG(0, 0, 0, 0); STG(0, 0, 0, 1); STG(0, 0, 0, 2); STG(0, 0, 0, 3);
  STG(1, 0, 0, 0); STG(1, 0, 0, 1); STG(1, 0, 0, 2); STG(1, 0, 0, 3);
  STG(0, 1, 1, 0); STG(0, 1, 1, 1); STG(0, 1, 1, 2); STG(0, 1, 1, 3);
  STG(1, 1, 1, 0); STG(1, 1, 1, 1); STG(1, 1, 1, 2); STG(1, 1, 1, 3);
  asm volatile("s_waitcnt vmcnt(8)" ::: "memory");  // tile0 done; tile1 in flight
  __builtin_amdgcn_s_barrier();
  __builtin_amdgcn_sched_barrier(0);

  for (int kt = 0; kt < NT - 2; kt += 2) {
    TILE(kt, 0, 1, 1);
    TILE(kt + 1, 1, 1, 1);
  }
  TILE(NT - 2, 0, 0, 1);  // vmcnt(0): drains last tile's staging
  TILE(NT - 1, 1, 0, 0);

  // epilogue: lane holds rows i = base..base+3 (contiguous), col j = lr per 16x16 tile
  if (MODE == 1) {
#pragma unroll
    for (int mi = 0; mi < 8; ++mi) {
      int ih = i0 + (wm << 7) + (mi << 4) + (q << 2);
      floatx4 bb = *(const floatx4*)&bias[ih];
#pragma unroll
      for (int nj = 0; nj < 4; ++nj) {
        int j = j0 + (wn << 6) + (nj << 4) + lr;
        floatx4 v = acc[mi][nj];
        half4v hv;
#pragma unroll
        for (int r = 0; r < 4; ++r) hv[r] = (_Float16)fmaxf(v[r] + bb[r], 0.f);
        *(half4v*)&outp[(size_t)j * 1024 + ih] = hv;  // H1[m][h..h+3]
      }
    }
  } else {
#pragma unroll
    for (int nj = 0; nj < 4; ++nj) {
      int j = j0 + (wn << 6) + (nj << 4) + lr;  // h
      float bj = bias[j];
#pragma unroll
      for (int mi = 0; mi < 8; ++mi) {
        int im = i0 + (wm << 7) + (mi << 4) + (q << 2);  // m
        int bb = im >> 10, n = im & 1023;
        floatx4 v = acc[mi][nj];
        half4v hv;
#pragma unroll
        for (int r = 0; r < 4; ++r) hv[r] = (_Float16)(v[r] + bj);
        *(half4v*)&outp[((size_t)bb << 20) + ((size_t)j << 10) + (size_t)n] = hv;
      }
    }
  }
}

// ---------------- Trim v3: count-only histogram + in-register sums ----------------
// One wave per column (b,h). 1024 u32 count bins (16 KB/block -> 10 blocks/CU).
// Locate boundary bins from count scan; all sums (s(b1), s(b2), mid-sum) computed
// in-register via predicated wave reductions over the 16 loaded values/lane.
// Physical slot of logical uint4-chunk j of lane L: L*4 + (j ^ ((L>>1)&3))  (2-way
// free bank pattern for the b128 init/readback).
#define NB 1024
__global__ __launch_bounds__(256) void trim_kernel(const _Float16* __restrict__ encT,
                                                   const int* __restrict__ nv_arr,
                                                   const int* __restrict__ k_arr,
                                                   float* __restrict__ agg) {
  __shared__ unsigned int cnt[4 * NB];  // 16 KB, wave-private slices
  int t = threadIdx.x, lane = t & 63, w = t >> 6;
  int blk = blockIdx.x;
  int batch = blk >> 8;
  int h = ((blk & 255) << 2) + w;
  unsigned int* cw = cnt + w * NB;
  uint4* cp = (uint4*)cw;
  {
    uint4 z = {0u, 0u, 0u, 0u};
#pragma unroll
    for (int i = 0; i < 4; ++i) cp[lane * 4 + (i ^ ((lane >> 1) & 3))] = z;
  }

  int nv = nv_arr[batch], kk = k_arr[batch];
  const _Float16* col = encT + ((size_t)batch << 20) + ((size_t)h << 10);
  const uint4* p = (const uint4*)col + lane * 2;
  uint4 u0 = p[0], u1 = p[1];
  unsigned vals[8] = {u0.x, u0.y, u0.z, u0.w, u1.x, u1.y, u1.z, u1.w};
  int nvalid = nv - lane * 16;  // may be <=0 or >=16

  float vv[16];
  int bn[16];
#pragma unroll
  for (int d = 0; d < 8; ++d) {
    unsigned u = vals[d];
#pragma unroll
    for (int sub = 0; sub < 2; ++sub) {
      int idx = d * 2 + sub;
      unsigned short bits = (unsigned short)(sub ? (u >> 16) : (u & 0xffffu));
      _Float16 hvv;
      __builtin_memcpy(&hvv, &bits, 2);
      float v = (float)hvv;
      if (idx < nvalid) {
        v = fminf(fmaxf(v, -8.0f), 7.999f);
        int bin = (int)((v + 8.0f) * 64.0f);
        bin = min(NB - 1, bin);
        vv[idx] = v;
        bn[idx] = bin;
        int Lb = bin >> 4, jc = (bin >> 2) & 3;
        int phys = ((Lb << 2) + (jc ^ ((Lb >> 1) & 3))) * 4 + (bin & 3);
        atomicAdd(&cw[phys], 1u);
      } else {
        vv[idx] = 0.f;
        bn[idx] = -1;
      }
    }
  }

  // readback own 16 counts (logical bins [lane*16, lane*16+16))
  int c[16];
  {
    uint4 rb[4];
#pragma unroll
    for (int i = 0; i < 4; ++i) rb[i] = cp[lane * 4 + (i ^ ((lane >> 1) & 3))];
#pragma unroll
    for (int i = 0; i < 4; ++i) {
      c[4 * i] = (int)rb[i].x; c[4 * i + 1] = (int)rb[i].y;
      c[4 * i + 2] = (int)rb[i].z; c[4 * i + 3] = (int)rb[i].w;
    }
  }
  int ct = 0;
#pragma unroll
  for (int i = 0; i < 16; ++i) ct += c[i];
  // exclusive scan of chunk totals across lanes
  int ci = ct;
#pragma unroll
  for (int off = 1; off < 64; off <<= 1) {
    int cu = __shfl_up(ci, off, 64);
    if (lane >= off) ci += cu;
  }
  int cex = ci - ct;
  int r1 = kk, r2 = nv - kk;
  // locate boundary bins; pack (bin<<12)|cex_at_bin, broadcast via max-reduce
  int p1 = -1, p2 = -1;
  {
    int run = cex;
#pragma unroll
    for (int i = 0; i < 16; ++i) {
      int cc = c[i];
      if (run < r1 && r1 <= run + cc) p1 = ((lane * 16 + i) << 12) | run;
      if (run < r2 && r2 <= run + cc) p2 = ((lane * 16 + i) << 12) | run;
      run += cc;
    }
  }
#pragma unroll
  for (int off = 32; off > 0; off >>= 1) {
    p1 = max(p1, __shfl_xor(p1, off, 64));
    p2 = max(p2, __shfl_xor(p2, off, 64));
  }
  int b1 = p1 >> 12, cex1 = p1 & 4095;
  int b2 = p2 >> 12, cex2 = p2 & 4095;
  // predicated in-register sums
  float s1 = 0.f, s2 = 0.f, tm = 0.f;
  int c1 = 0, c2 = 0;
#pragma unroll
  for (int i = 0; i < 16; ++i) {
    int b = bn[i];
    float v = vv[i];
    if (b == b1) { s1 += v; c1++; }
    if (b == b2) { s2 += v; c2++; }
    if (b > b1 && b < b2) tm += v;
  }
#pragma unroll
  for (int off = 32; off > 0; off >>= 1) {
    s1 += __shfl_xor(s1, off, 64);
    s2 += __shfl_xor(s2, off, 64);
    tm += __shfl_xor(tm, off, 64);
    c1 += __shfl_xor(c1, off, 64);
    c2 += __shfl_xor(c2, off, 64);
  }
  float mid;
  if (b1 == b2) {
    mid = (float)(r2 - r1) * (s1 / (float)c1);
  } else {
    mid = (float)(cex1 + c1 - r1) * (s1 / (float)c1) + tm +
          (float)(r2 - cex2) * (s2 / (float)c2);
  }
  if (lane == 0) {
    agg[(batch << 10) + h] = mid / (float)(nv - 2 * kk);
  }
}

// ---------------- Decode 1 (K-split GEMV): A3 = relu(agg @ W3 + b3) ----------------
__global__ __launch_bounds__(256) void decode1(const float* __restrict__ agg,
                                               const float* __restrict__ W3,
                                               const float* __restrict__ b3,
                                               float* __restrict__ A3) {
  __shared__ float al[1024];
  __shared__ float red[256];
  int b = blockIdx.x, hb = blockIdx.y, t = threadIdx.x;
  for (int i = t; i < 1024; i += 256) al[i] = agg[(b << 10) + i];
  __syncthreads();
  int hl = t & 63, ks = t >> 6;
  int h = hb * 64 + hl;
  const float* wp = W3 + (size_t)(ks * 256) * 1024 + h;
  const float* ap = al + ks * 256;
  float acc = 0.f;
#pragma unroll 8
  for (int k = 0; k < 256; ++k) acc = fmaf(ap[k], wp[(size_t)k * 1024], acc);
  red[t] = acc;
  __syncthreads();
  if (t < 64) {
    float s = red[t] + red[t + 64] + red[t + 128] + red[t + 192] + b3[hb * 64 + t];
    A3[(b << 10) + hb * 64 + t] = fmaxf(s, 0.f);
  }
}

__global__ void decode2(const float* __restrict__ A3, const float* __restrict__ W4,
                        const float* __restrict__ b4, float* __restrict__ outp) {
  __shared__ float red[4][10];
  int b = blockIdx.x, t = threadIdx.x, lane = t & 63, w = t >> 6;
  float part[10];
#pragma unroll
  for (int o = 0; o < 10; ++o) part[o] = 0.f;
#pragma unroll
  for (int jj = 0; jj < 4; ++jj) {
    int h2 = jj * 256 + t;
    float a = A3[(b << 10) + h2];
#pragma unroll
    for (int o = 0; o < 10; ++o) part[o] = fmaf(a, W4[h2 * 10 + o], part[o]);
  }
#pragma unroll
  for (int o = 0; o < 10; ++o)
#pragma unroll
    for (int off = 32; off > 0; off >>= 1) part[o] += __shfl_xor(part[o], off, 64);
  if (lane == 0)
#pragma unroll
    for (int o = 0; o < 10; ++o) red[w][o] = part[o];
  __syncthreads();
  if (t < 10) outp[b * 10 + t] = b4[t] + red[0][t] + red[1][t] + red[2][t] + red[3][t];
}

extern "C" void kernel_launch(void* const* d_in, const int* in_sizes, int n_in,
                              void* d_out, int out_size, void* d_ws, size_t ws_size,
                              hipStream_t stream) {
  const float* X = (const float*)d_in[0];
  const float* mask = (const float*)d_in[1];
  const float* W1 = (const float*)d_in[2];
  const float* b1 = (const float*)d_in[3];
  const float* W2 = (const float*)d_in[4];
  const float* b2 = (const float*)d_in[5];
  const float* W3 = (const float*)d_in[6];
  const float* b3 = (const float*)d_in[7];
  const float* W4 = (const float*)d_in[8];
  const float* b4 = (const float*)d_in[9];
  float* outp = (float*)d_out;
  char* ws = (char*)d_ws;

  _Float16* X16 = (_Float16*)(ws);
  _Float16* H1 = (_Float16*)(ws + 67108864ull);
  _Float16* encT = (_Float16*)(ws + 201326592ull);
  _Float16* W1T = (_Float16*)(ws + 335544320ull);
  _Float16* W2T = (_Float16*)(ws + 336592896ull);
  float* agg = (float*)(ws + 338690048ull);
  float* A3 = (float*)(ws + 338952192ull);
  int* nv_arr = (int*)(ws + 339214336ull);
  int* k_arr = (int*)(ws + 339214592ull);

  prep_nv<<<64, 64, 0, stream>>>(mask, nv_arr, k_arr);
  preprocess<<<16768, 256, 0, stream>>>(X, X16, W1, W1T, W2, W2T, nv_arr);
  gemm_kernel<512, 1><<<1024, 512, 0, stream>>>(W1T, X16, b1, nv_arr, H1);
  gemm_kernel<1024, 2><<<1024, 512, 0, stream>>>(H1, W2T, b2, nv_arr, encT);
  trim_kernel<<<16384, 256, 0, stream>>>(encT, nv_arr, k_arr, agg);
  decode1<<<dim3(64, 16), 256, 0, stream>>>(agg, W3, b3, A3);
  decode2<<<64, 256, 0, stream>>>(A3, W4, b4, outp);
}